// Round 2
// baseline (594.589 us; speedup 1.0000x reference)
//
#include <hip/hip_runtime.h>
#include <math.h>

#define N_NODES 10000
#define F_IN_D  256
#define H_DIM   128
#define C_OUTD  40
#define NLAYERS 3
#define NHEADS  8
#define DHD     16
#define NEDGES  160000
#define ETOT    (NEDGES + N_NODES)
#define SCALE_F 0.25f  /* 1/sqrt(16) */

// ---------------- graph preprocessing ----------------

__global__ void k_deg_init(int* degi) {
    int i = blockIdx.x * 256 + threadIdx.x;
    if (i < N_NODES) degi[i] = 1;  // self-loop
}

__global__ void k_deg_count(const int* __restrict__ col, int* degi) {
    int e = blockIdx.x * 256 + threadIdx.x;
    if (e < NEDGES) atomicAdd(&degi[col[e]], 1);
}

__global__ void k_dis(const int* __restrict__ degi, float* dis) {
    int i = blockIdx.x * 256 + threadIdx.x;
    if (i < N_NODES) dis[i] = rsqrtf((float)degi[i]);
}

// single-block exclusive scan over degrees -> CSR offsets; also zeroes cursors
__global__ void k_scan(const int* __restrict__ degi, int* offsets, int* cursor) {
    __shared__ int part[256];
    int tid = threadIdx.x;
    const int CH = (N_NODES + 255) / 256;  // 40
    int beg = tid * CH;
    int end = beg + CH; if (end > N_NODES) end = N_NODES;
    int s = 0;
    for (int i = beg; i < end; ++i) s += degi[i];
    part[tid] = s;
    __syncthreads();
    for (int off = 1; off < 256; off <<= 1) {
        int v = 0;
        if (tid >= off) v = part[tid - off];
        __syncthreads();
        part[tid] += v;
        __syncthreads();
    }
    int base = part[tid] - s;  // exclusive prefix
    for (int i = beg; i < end; ++i) {
        offsets[i] = base;
        cursor[i]  = 0;
        base += degi[i];
    }
}

__global__ void k_scatter(const int* __restrict__ row, const int* __restrict__ col,
                          const float* __restrict__ dis, const int* __restrict__ offsets,
                          int* cursor, int* csr_row, float* csr_norm) {
    int e = blockIdx.x * 256 + threadIdx.x;
    if (e >= ETOT) return;
    int r, c;
    if (e < NEDGES) { r = row[e]; c = col[e]; }
    else            { r = c = e - NEDGES; }   // self-loop
    int slot = offsets[c] + atomicAdd(&cursor[c], 1);
    csr_row[slot]  = r;
    csr_norm[slot] = dis[r] * dis[c];
}

// ---------------- dense GEMM: C[M x 128] = A[M x Kd] @ W[Kd x 128] + b ----------------
// block 256 threads, tile 64 rows x 128 cols, K-chunk 64

__global__ __launch_bounds__(256) void k_gemm(const float* __restrict__ A,
                                              const float* __restrict__ W,
                                              const float* __restrict__ bias,
                                              float* __restrict__ C,
                                              int M, int Kd, int do_relu) {
    __shared__ float As[64][68];   // +4 pad keeps float4 alignment, breaks pow2 stride
    __shared__ float Ws[64][128];
    int tid = threadIdx.x;
    int row0 = blockIdx.x * 64;
    int tr = tid >> 5;     // 0..7  row group (8 rows each)
    int tc = tid & 31;     // 0..31 col group (4 cols each)

    float acc[8][4];
    #pragma unroll
    for (int i = 0; i < 8; ++i)
        #pragma unroll
        for (int j = 0; j < 4; ++j) acc[i][j] = 0.f;

    for (int k0 = 0; k0 < Kd; k0 += 64) {
        // stage A tile (64 x 64)
        #pragma unroll
        for (int it = 0; it < 4; ++it) {
            int f = tid + 256 * it;
            int r = f >> 4, kv = f & 15;
            float4 a4 = make_float4(0.f, 0.f, 0.f, 0.f);
            int ar = row0 + r;
            if (ar < M) a4 = *(const float4*)&A[(size_t)ar * Kd + k0 + kv * 4];
            *(float4*)&As[r][kv * 4] = a4;
        }
        // stage W tile (64 x 128)
        #pragma unroll
        for (int it = 0; it < 8; ++it) {
            int f = tid + 256 * it;
            int kr = f >> 5, cv = f & 31;
            *(float4*)&Ws[kr][cv * 4] = *(const float4*)&W[(size_t)(k0 + kr) * H_DIM + cv * 4];
        }
        __syncthreads();
        #pragma unroll
        for (int kk = 0; kk < 64; kk += 4) {
            float4 w0 = *(const float4*)&Ws[kk + 0][tc * 4];
            float4 w1 = *(const float4*)&Ws[kk + 1][tc * 4];
            float4 w2 = *(const float4*)&Ws[kk + 2][tc * 4];
            float4 w3 = *(const float4*)&Ws[kk + 3][tc * 4];
            #pragma unroll
            for (int i = 0; i < 8; ++i) {
                float4 a = *(const float4*)&As[tr * 8 + i][kk];
                acc[i][0] += a.x * w0.x + a.y * w1.x + a.z * w2.x + a.w * w3.x;
                acc[i][1] += a.x * w0.y + a.y * w1.y + a.z * w2.y + a.w * w3.y;
                acc[i][2] += a.x * w0.z + a.y * w1.z + a.z * w2.z + a.w * w3.z;
                acc[i][3] += a.x * w0.w + a.y * w1.w + a.z * w2.w + a.w * w3.w;
            }
        }
        __syncthreads();
    }

    float4 b4 = *(const float4*)&bias[tc * 4];
    #pragma unroll
    for (int i = 0; i < 8; ++i) {
        int r = row0 + tr * 8 + i;
        if (r < M) {
            float4 o;
            o.x = acc[i][0] + b4.x; o.y = acc[i][1] + b4.y;
            o.z = acc[i][2] + b4.z; o.w = acc[i][3] + b4.w;
            if (do_relu) {
                o.x = fmaxf(o.x, 0.f); o.y = fmaxf(o.y, 0.f);
                o.z = fmaxf(o.z, 0.f); o.w = fmaxf(o.w, 0.f);
            }
            *(float4*)&C[(size_t)r * H_DIM + tc * 4] = o;
        }
    }
}

// ---------------- fused per-node attention aggregation ----------------
// one block (128 threads = 8 heads x 16 dims) per destination node
// Q layout: [N][128]; K,V layout: [s][N][128]

template <int T>
__global__ __launch_bounds__(128) void k_attn_agg(const float* __restrict__ Q,
                                                  const float* __restrict__ K,
                                                  const float* __restrict__ V,
                                                  const int* __restrict__ csr_row,
                                                  const float* __restrict__ csr_norm,
                                                  const int* __restrict__ offsets,
                                                  const int* __restrict__ degi,
                                                  float* __restrict__ Xout) {
    int n = blockIdx.x;
    int tid = threadIdx.x;               // h = tid>>4, d = tid&15
    float qv = Q[(size_t)n * H_DIM + tid] * SCALE_F;
    int start = offsets[n];
    int cnt   = degi[n];
    float acc = 0.f;

    for (int j = 0; j < cnt; ++j) {
        int   r   = csr_row[start + j];
        float nrm = csr_norm[start + j];
        float sc[T];
        #pragma unroll
        for (int s = 0; s < T; ++s) {
            float p = qv * K[((size_t)s * N_NODES + r) * H_DIM + tid];
            p += __shfl_xor(p, 1, 16);
            p += __shfl_xor(p, 2, 16);
            p += __shfl_xor(p, 4, 16);
            p += __shfl_xor(p, 8, 16);
            sc[s] = p;                   // all 16 lanes hold full head-dot
        }
        float m = 0.f;
        #pragma unroll
        for (int s = 0; s < T; ++s) m = fmaxf(m, sc[s]);
        float den = expf(-m);            // restricted-softmax null slot
        float mv = 0.f;
        #pragma unroll
        for (int s = 0; s < T; ++s) {
            float wgt = expf(sc[s] - m);
            den += wgt;
            mv  += wgt * V[((size_t)s * N_NODES + r) * H_DIM + tid];
        }
        acc += nrm * mv / den;
    }
    Xout[(size_t)n * H_DIM + tid] = fmaxf(acc, 0.f);  // relu
}

// ---------------- fused lin2 + log_softmax ----------------
// one wave (64 lanes) per node, 4 nodes per 256-thread block

__global__ __launch_bounds__(256) void k_lin2(const float* __restrict__ X,
                                              const float* __restrict__ W2,
                                              const float* __restrict__ b2,
                                              float* __restrict__ out) {
    int lane = threadIdx.x & 63;
    int n = blockIdx.x * 4 + (threadIdx.x >> 6);
    if (n >= N_NODES) return;            // whole wave exits together
    float acc = (lane < C_OUTD) ? b2[lane] : 0.f;
    for (int k = 0; k < H_DIM; ++k) {
        float xv = X[(size_t)n * H_DIM + k];
        if (lane < C_OUTD) acc += xv * W2[k * C_OUTD + lane];
    }
    float lg = (lane < C_OUTD) ? acc : -INFINITY;
    float m = lg;
    #pragma unroll
    for (int o = 32; o > 0; o >>= 1) m = fmaxf(m, __shfl_xor(m, o, 64));
    float e = (lane < C_OUTD) ? expf(lg - m) : 0.f;
    float ssum = e;
    #pragma unroll
    for (int o = 32; o > 0; o >>= 1) ssum += __shfl_xor(ssum, o, 64);
    float lse = m + logf(ssum);
    if (lane < C_OUTD) out[(size_t)n * C_OUTD + lane] = lg - lse;
}

// ---------------- launcher ----------------

extern "C" void kernel_launch(void* const* d_in, const int* in_sizes, int n_in,
                              void* d_out, int out_size, void* d_ws, size_t ws_size,
                              hipStream_t stream) {
    const int*   ei      = (const int*)d_in[0];
    const int*   row     = ei;
    const int*   col     = ei + NEDGES;
    const float* x_param = (const float*)d_in[1];
    const float* lin1_w  = (const float*)d_in[2];
    const float* lin1_b  = (const float*)d_in[3];
    const float* wq      = (const float*)d_in[4];
    const float* wk      = (const float*)d_in[5];
    const float* wv      = (const float*)d_in[6];
    const float* bq      = (const float*)d_in[7];
    const float* bk      = (const float*)d_in[8];
    const float* bv      = (const float*)d_in[9];
    const float* lin2_w  = (const float*)d_in[10];
    const float* lin2_b  = (const float*)d_in[11];
    float*       out     = (float*)d_out;

    char* wbase = (char*)d_ws;
    size_t off = 0;
    auto alloc = [&](size_t bytes) -> void* {
        off = (off + 255) & ~(size_t)255;
        void* p = wbase + off;
        off += bytes;
        return p;
    };
    int*   degi     = (int*)  alloc((size_t)N_NODES * 4);
    float* dis      = (float*)alloc((size_t)N_NODES * 4);
    int*   offsets  = (int*)  alloc((size_t)N_NODES * 4);
    int*   cursor   = (int*)  alloc((size_t)N_NODES * 4);
    int*   csr_row  = (int*)  alloc((size_t)ETOT * 4);
    float* csr_norm = (float*)alloc((size_t)ETOT * 4);
    float* XH       = (float*)alloc((size_t)4 * N_NODES * H_DIM * 4);  // x0..x3
    float* Qb       = (float*)alloc((size_t)N_NODES * H_DIM * 4);
    float* Kb       = (float*)alloc((size_t)3 * N_NODES * H_DIM * 4);
    float* Vb       = (float*)alloc((size_t)3 * N_NODES * H_DIM * 4);

    // graph preprocessing (shared by all 3 layers)
    k_deg_init <<<(N_NODES + 255) / 256, 256, 0, stream>>>(degi);
    k_deg_count<<<(NEDGES + 255) / 256, 256, 0, stream>>>(col, degi);
    k_dis      <<<(N_NODES + 255) / 256, 256, 0, stream>>>(degi, dis);
    k_scan     <<<1, 256, 0, stream>>>(degi, offsets, cursor);
    k_scatter  <<<(ETOT + 255) / 256, 256, 0, stream>>>(row, col, dis, offsets, cursor,
                                                        csr_row, csr_norm);

    int gb1 = (N_NODES + 63) / 64;
    // x0 = relu(x_param @ lin1_w + lin1_b)
    k_gemm<<<gb1, 256, 0, stream>>>(x_param, lin1_w, lin1_b, XH, N_NODES, F_IN_D, 1);

    for (int l = 0; l < NLAYERS; ++l) {
        int t  = l + 1;
        int Mt = t * N_NODES;
        int gbt = (Mt + 63) / 64;
        // q from latest slice; k,v batched over all t history slices (same weights)
        k_gemm<<<gb1, 256, 0, stream>>>(XH + (size_t)l * N_NODES * H_DIM,
                                        wq + (size_t)l * H_DIM * H_DIM, bq + l * H_DIM,
                                        Qb, N_NODES, H_DIM, 0);
        k_gemm<<<gbt, 256, 0, stream>>>(XH, wk + (size_t)l * H_DIM * H_DIM, bk + l * H_DIM,
                                        Kb, Mt, H_DIM, 0);
        k_gemm<<<gbt, 256, 0, stream>>>(XH, wv + (size_t)l * H_DIM * H_DIM, bv + l * H_DIM,
                                        Vb, Mt, H_DIM, 0);
        float* Xnext = XH + (size_t)(l + 1) * N_NODES * H_DIM;
        if (t == 1)
            k_attn_agg<1><<<N_NODES, 128, 0, stream>>>(Qb, Kb, Vb, csr_row, csr_norm,
                                                       offsets, degi, Xnext);
        else if (t == 2)
            k_attn_agg<2><<<N_NODES, 128, 0, stream>>>(Qb, Kb, Vb, csr_row, csr_norm,
                                                       offsets, degi, Xnext);
        else
            k_attn_agg<3><<<N_NODES, 128, 0, stream>>>(Qb, Kb, Vb, csr_row, csr_norm,
                                                       offsets, degi, Xnext);
    }

    k_lin2<<<(N_NODES + 3) / 4, 256, 0, stream>>>(XH + (size_t)3 * N_NODES * H_DIM,
                                                  lin2_w, lin2_b, out);
}